// Round 12
// baseline (255.479 us; speedup 1.0000x reference)
//
#include <hip/hip_runtime.h>
#include <math.h>

#define N_NODES 100000
#define N_EDGES 1600000
#define IN_F    128
#define NH1     8
#define HID     8
#define C1      64   // NH1*HID
#define C2      40   // N_CLASSES

// counting-sort CSR build
#define EB      2048                               // edges per block (pass A/C)
#define B1      ((N_EDGES + EB - 1) / EB)          // 782 blocks
#define NPB     128                                // nodes per coarse bin
#define NBIN    ((N_NODES + NPB - 1) / NPB)        // 782 coarse bins (dst>>7)
#define NBIN4   784                                // NBIN padded to x4 (int4 colscan)
#define S2CAP   2560                               // scatter2 LDS bucket cap

// merged grid splits
#define WPREP_BLKS 44                              // ceil((8192+3072)/256)
#define GEMM1_BLKS ((N_NODES / 16 + 3) / 4)        // 1563
#define NPAIR   (N_NODES / 2)                      // 50000 node pairs

typedef unsigned short ushort_t;
typedef unsigned int uint_t;
typedef _Float16 half_t;
typedef short short8 __attribute__((ext_vector_type(8)));
typedef float f32x4 __attribute__((ext_vector_type(4)));
typedef int i32x4 __attribute__((ext_vector_type(4)));

__device__ __forceinline__ float lrelu(float x) { return x > 0.f ? x : 0.2f * x; }
__device__ __forceinline__ ushort_t f2bf(float f) {
    uint_t u = __float_as_uint(f);
    u = (u + 0x7FFFu + ((u >> 16) & 1u)) >> 16;   // round-to-nearest-even
    return (ushort_t)u;
}
__device__ __forceinline__ float bf2f(ushort_t s) {
    return __uint_as_float(((uint_t)s) << 16);
}
__device__ __forceinline__ short8 ld8f2bf(const float* p) {
    float4 a = *(const float4*)p;
    float4 b = *(const float4*)(p + 4);
    ushort_t o[8] = {f2bf(a.x), f2bf(a.y), f2bf(a.z), f2bf(a.w),
                     f2bf(b.x), f2bf(b.y), f2bf(b.z), f2bf(b.w)};
    return *(const short8*)o;
}

// ---- merged: hist1 (first) + W1/W2 pre-swizzle.
//      Hblk layout [B1][NBIN4]: hist writes + scatter1 reads coalesced;
//      pad columns (NBIN..NBIN4) are zeros so int4 colscan is clean. ----
__global__ __launch_bounds__(256) void k_prep_hist(
    const float* __restrict__ W1, ushort_t* __restrict__ W1p,
    const float* __restrict__ W2, ushort_t* __restrict__ W2p,
    const int* __restrict__ ei, int* __restrict__ Hblk)
{
    int b = blockIdx.x;
    if (b < B1) {
        __shared__ int h[NBIN4];
        for (int i = threadIdx.x; i < NBIN4; i += 256) h[i] = 0;
        __syncthreads();
        int base = b * EB;
        for (int i = threadIdx.x; i < EB; i += 256) {
            int idx = base + i;
            if (idx < N_EDGES) atomicAdd(&h[((uint_t)ei[N_EDGES + idx]) >> 7], 1);
        }
        __syncthreads();
        for (int i = threadIdx.x; i < NBIN4; i += 256)
            Hblk[b * NBIN4 + i] = h[i];                // coalesced
        return;
    }
    int i = (b - B1) * 256 + threadIdx.x;
    if (i < 8192) {
        int j = i & 7, lane = (i >> 3) & 63, nt = (i >> 9) & 3, s = i >> 11;
        int k = s * 32 + (lane >> 4) * 8 + j;
        int n = nt * 16 + (lane & 15);
        W1p[i] = f2bf(W1[k * C1 + n]);
    } else {
        int i2 = i - 8192;
        if (i2 < 3072) {
            int j = i2 & 7, lane = (i2 >> 3) & 63, khalf = (i2 >> 9) & 1, nt = i2 >> 10;
            int n = nt * 16 + (lane & 15);
            int k = khalf * 32 + (lane >> 4) * 8 + j;
            float v = (n < C2) ? W2[k * C2 + n] : 0.f;
            W2p[i2] = f2bf(v);
        }
    }
}

// ---- colscan: 4 bins per block via int4 componentwise scan ----
__global__ __launch_bounds__(512) void k_colscan(
    int* __restrict__ Hblk, int* __restrict__ totB)
{
    __shared__ i32x4 s[512];
    int g = blockIdx.x * 4;            // bin group base
    int t = threadIdx.x;
    i32x4 run = {0, 0, 0, 0};
    for (int c = 0; c < 2; ++c) {
        int i = c * 512 + t;
        i32x4 v = {0, 0, 0, 0};
        if (i < B1) v = *(const i32x4*)&Hblk[i * NBIN4 + g];
        s[t] = v;
        __syncthreads();
        for (int off = 1; off < 512; off <<= 1) {
            i32x4 u = {0, 0, 0, 0};
            if (t >= off) u = s[t - off];
            __syncthreads();
            s[t] += u;
            __syncthreads();
        }
        if (i < B1) *(i32x4*)&Hblk[i * NBIN4 + g] = s[t] - v + run;
        i32x4 tot = s[511];
        __syncthreads();
        run += tot;
    }
    if (t == 0) *(i32x4*)&totB[g] = run;
}

// ---- basescan: exclusive scan of 782 bin totals ----
__global__ __launch_bounds__(512) void k_basescan(
    const int* __restrict__ totB, int* __restrict__ baseB,
    int* __restrict__ rowptr)
{
    __shared__ int s[512];
    int t = threadIdx.x;
    int run = 0;
    for (int c = 0; c < 2; ++c) {
        int i = c * 512 + t;
        int v = (i < NBIN) ? totB[i] : 0;
        s[t] = v;
        __syncthreads();
        for (int off = 1; off < 512; off <<= 1) {
            int u = (t >= off) ? s[t - off] : 0;
            __syncthreads();
            s[t] += u;
            __syncthreads();
        }
        if (i < NBIN) baseB[i] = s[t] - v + run;
        int tot = s[511];
        __syncthreads();
        run += tot;
    }
    if (t == 0) { baseB[NBIN] = run; rowptr[N_NODES] = run; }
}

// ---- merged: scatter1 (block-local counting sort, first) || GEMM1 ----
__global__ __launch_bounds__(256) void k_gemm1_sc1(
    const float* __restrict__ x, const ushort_t* __restrict__ W1p,
    const float* __restrict__ as1, const float* __restrict__ ad1,
    ushort_t* __restrict__ H1, float* __restrict__ s1, float* __restrict__ d1,
    const int* __restrict__ ei, const float* __restrict__ ea,
    const int* __restrict__ Hblk, const int* __restrict__ baseB,
    int2* __restrict__ coarse)
{
    int b = blockIdx.x;
    int t = threadIdx.x;
    if (b < B1) {
        __shared__ int    cnt[NBIN];     // hist, then cursor
        __shared__ int    loff[NBIN];    // local exclusive offsets
        __shared__ int    gof[NBIN];     // global base - loff
        __shared__ int    ssc[256];
        __shared__ int2   sbuf[EB];      // 16 KB bin-sorted edges
        __shared__ ushort_t sbin[EB];    // 4 KB bin ids
        int base = b * EB;
        int nE = min(EB, N_EDGES - base);
        for (int i = t; i < NBIN; i += 256) cnt[i] = 0;
        __syncthreads();
        int myb[EB / 256];
        #pragma unroll
        for (int c = 0; c < EB / 256; ++c) {
            int i = base + c * 256 + t;
            int bn = -1;
            if (i < N_EDGES) {
                bn = ((uint_t)ei[N_EDGES + i]) >> 7;
                atomicAdd(&cnt[bn], 1);
            }
            myb[c] = bn;
        }
        __syncthreads();
        {
            int b4 = t * 4;
            int a0 = (b4 + 0 < NBIN) ? cnt[b4 + 0] : 0;
            int a1 = (b4 + 1 < NBIN) ? cnt[b4 + 1] : 0;
            int a2 = (b4 + 2 < NBIN) ? cnt[b4 + 2] : 0;
            int a3 = (b4 + 3 < NBIN) ? cnt[b4 + 3] : 0;
            int tsum = a0 + a1 + a2 + a3;
            ssc[t] = tsum;
            __syncthreads();
            for (int off = 1; off < 256; off <<= 1) {
                int u = (t >= off) ? ssc[t - off] : 0;
                __syncthreads();
                ssc[t] += u;
                __syncthreads();
            }
            int exc = ssc[t] - tsum;
            if (b4 + 0 < NBIN) loff[b4 + 0] = exc;
            if (b4 + 1 < NBIN) loff[b4 + 1] = exc + a0;
            if (b4 + 2 < NBIN) loff[b4 + 2] = exc + a0 + a1;
            if (b4 + 3 < NBIN) loff[b4 + 3] = exc + a0 + a1 + a2;
        }
        __syncthreads();
        for (int i = t; i < NBIN; i += 256) {
            gof[i] = baseB[i] + Hblk[b * NBIN4 + i] - loff[i];
            cnt[i] = loff[i];
        }
        __syncthreads();
        #pragma unroll
        for (int c = 0; c < EB / 256; ++c) {
            int i = base + c * 256 + t;
            if (i < N_EDGES) {
                int bn = myb[c];
                int s = ei[i];
                int d = ei[N_EDGES + i];
                float e = ea[i];
                int p = atomicAdd(&cnt[bn], 1);
                sbuf[p] = make_int2(s | ((d & (NPB - 1)) << 24), __float_as_int(e));
                sbin[p] = (ushort_t)bn;
            }
        }
        __syncthreads();
        for (int j = t; j < nE; j += 256) {
            int bn = sbin[j];
            coarse[gof[bn] + j] = sbuf[j];
        }
        return;
    }
    // GEMM1 half: fragments from x (fp32) with in-register bf16 convert
    int tile = ((b - B1) * 256 + t) >> 6;
    int lane = t & 63;
    if (tile >= N_NODES / 16) return;
    int quad = lane >> 4, lo = lane & 15;
    const float* arow = x + ((size_t)tile * 16 + lo) * IN_F + quad * 8;
    short8 a0 = ld8f2bf(arow);                   // k = 0*32 + quad*8+j
    short8 a1 = ld8f2bf(arow + 32);
    short8 a2 = ld8f2bf(arow + 64);
    short8 a3 = ld8f2bf(arow + 96);
    f32x4 acc[4] = {{0,0,0,0},{0,0,0,0},{0,0,0,0},{0,0,0,0}};
    #pragma unroll
    for (int nt = 0; nt < 4; ++nt) {
        short8 b0 = *(const short8*)&W1p[((0 * 4 + nt) * 64 + lane) * 8];
        short8 b1 = *(const short8*)&W1p[((1 * 4 + nt) * 64 + lane) * 8];
        short8 b2 = *(const short8*)&W1p[((2 * 4 + nt) * 64 + lane) * 8];
        short8 b3 = *(const short8*)&W1p[((3 * 4 + nt) * 64 + lane) * 8];
        acc[nt] = __builtin_amdgcn_mfma_f32_16x16x32_bf16(a0, b0, acc[nt], 0, 0, 0);
        acc[nt] = __builtin_amdgcn_mfma_f32_16x16x32_bf16(a1, b1, acc[nt], 0, 0, 0);
        acc[nt] = __builtin_amdgcn_mfma_f32_16x16x32_bf16(a2, b2, acc[nt], 0, 0, 0);
        acc[nt] = __builtin_amdgcn_mfma_f32_16x16x32_bf16(a3, b3, acc[nt], 0, 0, 0);
    }
    int nb = tile * 16 + quad * 4;               // C/D: col=lo, row=quad*4+reg
    float ps[4][4], pd[4][4];
    #pragma unroll
    for (int nt = 0; nt < 4; ++nt) {
        int cb = nt * 16 + lo;
        float av = as1[cb], dv = ad1[cb];
        #pragma unroll
        for (int r = 0; r < 4; ++r) {
            H1[(size_t)(nb + r) * C1 + cb] = f2bf(acc[nt][r]);
            ps[nt][r] = acc[nt][r] * av;
            pd[nt][r] = acc[nt][r] * dv;
        }
    }
    #pragma unroll
    for (int nt = 0; nt < 4; ++nt)
        #pragma unroll
        for (int r = 0; r < 4; ++r)
            #pragma unroll
            for (int off = 1; off < 8; off <<= 1) {
                ps[nt][r] += __shfl_xor(ps[nt][r], off);
                pd[nt][r] += __shfl_xor(pd[nt][r], off);
            }
    if ((lo & 7) == 0) {
        int hh = lo >> 3;
        #pragma unroll
        for (int nt = 0; nt < 4; ++nt) {
            int h = nt * 2 + hh;
            #pragma unroll
            for (int r = 0; r < 4; ++r) {
                s1[(nb + r) * NH1 + h] = ps[nt][r];
                d1[(nb + r) * NH1 + h] = pd[nt][r];
            }
        }
    }
}

// ---- scatter2: one block per 128-node bucket (782 blocks) ----
__global__ __launch_bounds__(256) void k_scatter2(
    const int2* __restrict__ coarse, const int* __restrict__ baseB,
    int2* __restrict__ edges, int* __restrict__ rowptr)
{
    __shared__ int2 buf[S2CAP];          // 20 KB
    __shared__ int h[NPB];
    __shared__ int ssc[256];
    int bin = blockIdx.x, t = threadIdx.x;
    int s0 = baseB[bin], s1b = baseB[bin + 1];
    int n = s1b - s0;
    if (t < NPB) h[t] = 0;
    __syncthreads();
    for (int j = t; j < n; j += 256)
        atomicAdd(&h[(uint_t)coarse[s0 + j].x >> 24], 1);
    __syncthreads();
    int v = (t < NPB) ? h[t] : 0;
    ssc[t] = v;
    __syncthreads();
    for (int off = 1; off < 256; off <<= 1) {
        int u = (t >= off) ? ssc[t - off] : 0;
        __syncthreads();
        ssc[t] += u;
        __syncthreads();
    }
    int exc = ssc[t] - v;
    if (t < NPB) {
        int node = bin * NPB + t;
        if (node < N_NODES) rowptr[node] = s0 + exc;
        h[t] = exc;                      // h becomes cursor
    }
    __syncthreads();
    for (int j = t; j < n; j += 256) {
        int2 c = coarse[s0 + j];         // L2-hot second read
        int ln = (uint_t)c.x >> 24;
        int p = atomicAdd(&h[ln], 1);
        int2 ov = make_int2(c.x & 0x00FFFFFF, c.y);
        if (p < S2CAP) buf[p] = ov;
        else           edges[s0 + p] = ov;   // overflow fallback (~never)
    }
    __syncthreads();
    int nl = n < S2CAP ? n : S2CAP;
    for (int j = t; j < nl; j += 256)
        edges[s0 + j] = buf[j];              // coalesced write-out
}

// ============ attention / aggregation ============

// ---- K_node1 PAIRED (fused logit1), 16-deep gather unroll for MLP.
//      All 32 staging slots/half written each tile (pads: p=0, soff=0)
//      -> rounding steps to x16 is safe (pad gathers read row 0, add 0). ----
__global__ __launch_bounds__(256) void k_node1(
    const int* __restrict__ rowptr, const int2* __restrict__ edges,
    const float* __restrict__ s1, const float* __restrict__ d1,
    const float* __restrict__ ae1,
    const ushort_t* __restrict__ H1, ushort_t* __restrict__ out1r)
{
    __shared__ uint_t sm_s[4][2][33];     // +1 pad: halves hit distinct banks
    __shared__ float  sm_pf[4][2][8][33]; // [half][head][edge], +1 pad
    int w2 = (blockIdx.x * blockDim.x + threadIdx.x) >> 6;   // pair id
    int lane = threadIdx.x & 63;
    int wv = (threadIdx.x >> 6) & 3;
    if (w2 >= NPAIR) return;
    int half = lane >> 5, lo32 = lane & 31;
    int node = 2 * w2 + half;
    int h = lo32 >> 2;                     // head of features 2*lo32, 2*lo32+1
    uint_t fb = (uint_t)lo32 << 2;         // byte offset of this lane's dword
    int jb = rowptr[node], je = rowptr[node + 1];
    int cnt = je - jb;
    int maxc = max(cnt, __shfl_xor(cnt, 32));   // uniform loop bound
    float4 d1a = *(const float4*)(d1 + node * NH1);
    float4 d1b = *(const float4*)(d1 + node * NH1 + 4);
    float4 aea = *(const float4*)(ae1);
    float4 aeb = *(const float4*)(ae1 + 4);
    float den = 0.f, acc0 = 0.f, acc1 = 0.f;
    const float* pfh = &sm_pf[wv][half][h][0];
    const uint_t* sms = &sm_s[wv][half][0];
    for (int base = 0; base < maxc; base += 32) {
        int loc = base + lo32;
        uint_t soff = 0;
        float pf[8] = {0.f, 0.f, 0.f, 0.f, 0.f, 0.f, 0.f, 0.f};
        if (loc < cnt) {
            int2 ed = edges[jb + loc];
            soff = (uint_t)ed.x << 7;
            float ea = __int_as_float(ed.y);
            const float* s1r = s1 + (size_t)ed.x * NH1;
            float4 sa = *(const float4*)s1r;
            float4 sb = *(const float4*)(s1r + 4);
            pf[0] = __expf(lrelu(fmaf(ea, aea.x, sa.x + d1a.x)));
            pf[1] = __expf(lrelu(fmaf(ea, aea.y, sa.y + d1a.y)));
            pf[2] = __expf(lrelu(fmaf(ea, aea.z, sa.z + d1a.z)));
            pf[3] = __expf(lrelu(fmaf(ea, aea.w, sa.w + d1a.w)));
            pf[4] = __expf(lrelu(fmaf(ea, aeb.x, sb.x + d1b.x)));
            pf[5] = __expf(lrelu(fmaf(ea, aeb.y, sb.y + d1b.y)));
            pf[6] = __expf(lrelu(fmaf(ea, aeb.z, sb.z + d1b.z)));
            pf[7] = __expf(lrelu(fmaf(ea, aeb.w, sb.w + d1b.w)));
        }
        sm_s[wv][half][lo32] = soff;
        #pragma unroll
        for (int k = 0; k < 8; ++k) sm_pf[wv][half][k][lo32] = pf[k];
        __builtin_amdgcn_wave_barrier();
        int steps = (min(32, maxc - base) + 15) & ~15;   // pad slots have p=0
        for (int e = 0; e < steps; e += 16) {
            uint_t so[16];
            float  p[16];
            uint_t u[16];
            #pragma unroll
            for (int k = 0; k < 16; ++k) {
                so[k] = sms[e + k];
                p[k]  = pfh[e + k];
            }
            #pragma unroll
            for (int k = 0; k < 16; ++k)
                u[k] = *(const uint_t*)((const char*)H1 + (so[k] + fb));
            #pragma unroll
            for (int k = 0; k < 16; ++k) {
                den += p[k];
                acc0 = fmaf(p[k], __uint_as_float(u[k] << 16), acc0);
                acc1 = fmaf(p[k], __uint_as_float(u[k] & 0xffff0000u), acc1);
            }
        }
        __builtin_amdgcn_wave_barrier();
    }
    float inv = 1.f / (den + 1e-16f);
    float o0 = acc0 * inv, o1 = acc1 * inv;
    float r0 = o0 > 0.f ? o0 : __expf(o0) - 1.f;   // elu
    float r1 = o1 > 0.f ? o1 : __expf(o1) - 1.f;
    uint_t pk = (uint_t)f2bf(r0) | ((uint_t)f2bf(r1) << 16);
    *(uint_t*)((char*)out1r + (size_t)node * 128 + fb) = pk;   // all 64 lanes
}

// ---- K_gemm2 (MFMA): H2 PACKED to 40 cols (80-B rows) + s2/d2 dots.
//      cb>=40 stores must be guarded (packed layout). ----
__global__ __launch_bounds__(256) void k_gemm2(
    const ushort_t* __restrict__ out1r, const ushort_t* __restrict__ W2p,
    const float* __restrict__ as2, const float* __restrict__ ad2,
    ushort_t* __restrict__ H2, float* __restrict__ s2, float* __restrict__ d2)
{
    int tile = (blockIdx.x * blockDim.x + threadIdx.x) >> 6;
    int lane = threadIdx.x & 63;
    if (tile >= N_NODES / 16) return;
    int quad = lane >> 4, lo = lane & 15;
    const ushort_t* arow = out1r + ((size_t)tile * 16 + lo) * C1 + quad * 8;
    short8 a0 = *(const short8*)arow;
    short8 a1 = *(const short8*)(arow + 32);
    f32x4 acc[3] = {{0,0,0,0},{0,0,0,0},{0,0,0,0}};
    #pragma unroll
    for (int nt = 0; nt < 3; ++nt) {
        short8 b0 = *(const short8*)&W2p[((nt * 2 + 0) * 64 + lane) * 8];
        short8 b1 = *(const short8*)&W2p[((nt * 2 + 1) * 64 + lane) * 8];
        acc[nt] = __builtin_amdgcn_mfma_f32_16x16x32_bf16(a0, b0, acc[nt], 0, 0, 0);
        acc[nt] = __builtin_amdgcn_mfma_f32_16x16x32_bf16(a1, b1, acc[nt], 0, 0, 0);
    }
    float ps0 = 0.f, ps1 = 0.f, ps2 = 0.f, ps3 = 0.f;
    float pd0 = 0.f, pd1 = 0.f, pd2 = 0.f, pd3 = 0.f;
    #pragma unroll
    for (int nt = 0; nt < 3; ++nt) {
        int cb = nt * 16 + lo;
        bool ok = cb < C2;
        float a2 = ok ? as2[cb] : 0.f;
        float b2 = ok ? ad2[cb] : 0.f;
        float v0 = acc[nt][0], v1 = acc[nt][1], v2 = acc[nt][2], v3 = acc[nt][3];
        int nb = tile * 16 + quad * 4;
        if (ok) {
            H2[(size_t)(nb + 0) * C2 + cb] = f2bf(v0);
            H2[(size_t)(nb + 1) * C2 + cb] = f2bf(v1);
            H2[(size_t)(nb + 2) * C2 + cb] = f2bf(v2);
            H2[(size_t)(nb + 3) * C2 + cb] = f2bf(v3);
        }
        ps0 = fmaf(v0, a2, ps0); ps1 = fmaf(v1, a2, ps1);
        ps2 = fmaf(v2, a2, ps2); ps3 = fmaf(v3, a2, ps3);
        pd0 = fmaf(v0, b2, pd0); pd1 = fmaf(v1, b2, pd1);
        pd2 = fmaf(v2, b2, pd2); pd3 = fmaf(v3, b2, pd3);
    }
    #pragma unroll
    for (int off = 1; off < 16; off <<= 1) {
        ps0 += __shfl_xor(ps0, off); ps1 += __shfl_xor(ps1, off);
        ps2 += __shfl_xor(ps2, off); ps3 += __shfl_xor(ps3, off);
        pd0 += __shfl_xor(pd0, off); pd1 += __shfl_xor(pd1, off);
        pd2 += __shfl_xor(pd2, off); pd3 += __shfl_xor(pd3, off);
    }
    if (lo == 0) {
        int nb = tile * 16 + quad * 4;
        s2[nb + 0] = ps0; s2[nb + 1] = ps1; s2[nb + 2] = ps2; s2[nb + 3] = ps3;
        d2[nb + 0] = pd0; d2[nb + 1] = pd1; d2[nb + 2] = pd2; d2[nb + 3] = pd3;
    }
}

// ---- K_node2 PAIRED (fused logit2 + log_softmax), 8-deep gather unroll.
//      H2 packed (80-B rows): soff = src*80. ----
__global__ __launch_bounds__(256) void k_node2(
    const int* __restrict__ rowptr, const int2* __restrict__ edges,
    const float* __restrict__ s2, const float* __restrict__ d2,
    const float* __restrict__ ae2,
    const ushort_t* __restrict__ H2, float* __restrict__ out)
{
    __shared__ int2 sp[4][2][33];          // (src*80, p_float_bits), +1 pad
    int w2 = (blockIdx.x * blockDim.x + threadIdx.x) >> 6;
    int lane = threadIdx.x & 63;
    int wv = (threadIdx.x >> 6) & 3;
    if (w2 >= NPAIR) return;
    int half = lane >> 5, lo32 = lane & 31;
    int node = 2 * w2 + half;
    int fi = lo32 < 20 ? lo32 : 19;
    uint_t fb = (uint_t)fi << 2;
    int jb = rowptr[node], je = rowptr[node + 1];
    int cnt = je - jb;
    int maxc = max(cnt, __shfl_xor(cnt, 32));
    float d2v = d2[node];
    float aev = ae2[0];
    float den = 0.f, acc0 = 0.f, acc1 = 0.f;
    const int2* spp = &sp[wv][half][0];
    for (int base = 0; base < maxc; base += 32) {
        int loc = base + lo32;
        int soff = 0; float p = 0.f;
        if (loc < cnt) {
            int2 ed = edges[jb + loc];
            soff = ed.x * 80;                      // packed 80-B rows
            p = __expf(lrelu(s2[ed.x] + d2v + __int_as_float(ed.y) * aev));
        }
        sp[wv][half][lo32] = make_int2(soff, __float_as_int(p));
        __builtin_amdgcn_wave_barrier();
        int steps = (min(32, maxc - base) + 7) & ~7;   // pad slots have p=0
        for (int e = 0; e < steps; e += 8) {
            int2 ed[8];
            uint_t u[8];
            #pragma unroll
            for (int k = 0; k < 8; ++k) ed[k] = spp[e + k];
            #pragma unroll
            for (int k = 0; k < 8; ++k)
                u[k] = *(const uint_t*)((const char*)H2 + ((uint_t)ed[k].x + fb));
            #pragma unroll
            for (int k = 0; k < 8; ++k) {
                float pk = __int_as_float(ed[k].y);
                den += pk;
                acc0 = fmaf(pk, __uint_as_float(u[k] << 16), acc0);
                acc1 = fmaf(pk, __uint_as_float(u[k] & 0xffff0000u), acc1);
            }
        }
        __builtin_amdgcn_wave_barrier();
    }
    float inv = 1.f / (den + 1e-16f);
    float o0 = acc0 * inv, o1 = acc1 * inv;
    float v0 = lo32 < 20 ? o0 : -INFINITY;
    float v1 = lo32 < 20 ? o1 : -INFINITY;
    float m = fmaxf(v0, v1);
    #pragma unroll
    for (int off = 16; off; off >>= 1) m = fmaxf(m, __shfl_xor(m, off));
    float pp = lo32 < 20 ? __expf(v0 - m) + __expf(v1 - m) : 0.f;
    #pragma unroll
    for (int off = 16; off; off >>= 1) pp += __shfl_xor(pp, off);
    float ls = __logf(pp);
    if (lo32 < 20) {
        float2 st = make_float2(v0 - m - ls, v1 - m - ls);
        *(float2*)(out + (size_t)node * C2 + 2 * fi) = st;
    }
}

extern "C" void kernel_launch(void* const* d_in, const int* in_sizes, int n_in,
                              void* d_out, int out_size, void* d_ws, size_t ws_size,
                              hipStream_t stream)
{
    const float* x   = (const float*)d_in[0];
    const int*   ei  = (const int*)  d_in[1];
    const float* ea  = (const float*)d_in[2];
    const float* W1  = (const float*)d_in[3];
    const float* as1 = (const float*)d_in[4];
    const float* ad1 = (const float*)d_in[5];
    const float* ae1 = (const float*)d_in[6];
    const float* W2  = (const float*)d_in[7];
    const float* as2 = (const float*)d_in[8];
    const float* ad2 = (const float*)d_in[9];
    const float* ae2 = (const float*)d_in[10];
    float* out = (float*)d_out;

    // workspace layout (4-byte units):
    //   H1 [0,3.2M) -> reused as H2 packed (8 MB, k_gemm2 writes after
    //     node1 reads H1); out1r region [3.2M,6.4M) first holds CSR temps
    //     (Hblk 782*784 ints, totB, baseB), then out1r (k_node1 writes)
    //   coarse [6.4M,9.6M); edges [9.6M,12.8M)
    float*    ws     = (float*)d_ws;
    ushort_t* H1     = (ushort_t*)ws;                 // [0, 3.2M)  bf16
    ushort_t* H2     = (ushort_t*)ws;                 //   alias, packed 40-col
    ushort_t* out1r  = (ushort_t*)(ws + 3200000);     // [3.2M, 6.4M)
    int*      Hblk   = (int*)(ws + 3200000);          //   alias: 782*784 ints
    int*      totB   = (int*)(ws + 3820000);          //   alias: 784 ints
    int*      baseB  = (int*)(ws + 3821000);          //   alias: 783 ints
    int2*     coarse = (int2*)(ws + 6400000);         // [6.4M, 9.6M) packed
    int2*     edges  = (int2*)(ws + 9600000);         // [9.6M, 12.8M)
    float*    s1     = ws + 16000000;                 // [16.0M, 16.8M)
    float*    d1     = ws + 16800000;                 // [16.8M, 17.6M)
    int*      rowptr = (int*)(ws + 17600000);         // 100,001 ints
    float*    s2     = ws + 17700008;                 // 100,000
    float*    d2     = ws + 17800008;                 // 100,000
    ushort_t* W2p    = (ushort_t*)(ws + 17900008);    // 3072 bf16 (1536 w)
    ushort_t* W1p    = (ushort_t*)(ws + 17901544);    // 8192 bf16 (4096 w)

    k_prep_hist <<<B1 + WPREP_BLKS, 256, 0, stream>>>(
        W1, W1p, W2, W2p, ei, Hblk);
    k_colscan   <<<NBIN4 / 4, 512, 0, stream>>>(Hblk, totB);
    k_basescan  <<<1, 512, 0, stream>>>(totB, baseB, rowptr);
    k_gemm1_sc1 <<<B1 + GEMM1_BLKS, 256, 0, stream>>>(
        x, W1p, as1, ad1, H1, s1, d1, ei, ea, Hblk, baseB, coarse);
    k_scatter2  <<<NBIN, 256, 0, stream>>>(coarse, baseB, edges, rowptr);
    k_node1     <<<(NPAIR + 3) / 4, 256, 0, stream>>>(rowptr, edges, s1, d1, ae1,
                                                      H1, out1r);
    k_gemm2     <<<(N_NODES / 16 + 3) / 4, 256, 0, stream>>>(out1r, W2p, as2, ad2,
                                                             H2, s2, d2);
    k_node2     <<<(NPAIR + 3) / 4, 256, 0, stream>>>(rowptr, edges, s2, d2, ae2,
                                                      H2, out);
}

// Round 13
// 249.339 us; speedup vs baseline: 1.0246x; 1.0246x over previous
//
#include <hip/hip_runtime.h>
#include <math.h>

#define N_NODES 100000
#define N_EDGES 1600000
#define IN_F    128
#define NH1     8
#define HID     8
#define C1      64   // NH1*HID
#define C2      40   // N_CLASSES

// counting-sort CSR build
#define EB      2048                               // edges per block (pass A/C)
#define B1      ((N_EDGES + EB - 1) / EB)          // 782 blocks
#define NPB     128                                // nodes per coarse bin
#define NBIN    ((N_NODES + NPB - 1) / NPB)        // 782 coarse bins (dst>>7)
#define NBIN4   784                                // NBIN padded to x4 (int4 colscan)
#define S2CAP   2560                               // scatter2 LDS bucket cap

// merged grid splits
#define WPREP_BLKS 44                              // ceil((8192+3072)/256)
#define GEMM1_BLKS ((N_NODES / 16 + 3) / 4)        // 1563
#define NPAIR   (N_NODES / 2)                      // 50000 node pairs

typedef unsigned short ushort_t;
typedef unsigned int uint_t;
typedef _Float16 half_t;
typedef short short8 __attribute__((ext_vector_type(8)));
typedef float f32x4 __attribute__((ext_vector_type(4)));
typedef int i32x4 __attribute__((ext_vector_type(4)));

__device__ __forceinline__ float lrelu(float x) { return x > 0.f ? x : 0.2f * x; }
__device__ __forceinline__ ushort_t f2bf(float f) {
    uint_t u = __float_as_uint(f);
    u = (u + 0x7FFFu + ((u >> 16) & 1u)) >> 16;   // round-to-nearest-even
    return (ushort_t)u;
}
__device__ __forceinline__ float bf2f(ushort_t s) {
    return __uint_as_float(((uint_t)s) << 16);
}
__device__ __forceinline__ short8 ld8f2bf(const float* p) {
    float4 a = *(const float4*)p;
    float4 b = *(const float4*)(p + 4);
    ushort_t o[8] = {f2bf(a.x), f2bf(a.y), f2bf(a.z), f2bf(a.w),
                     f2bf(b.x), f2bf(b.y), f2bf(b.z), f2bf(b.w)};
    return *(const short8*)o;
}

// ---- merged: hist1 (first) + W1/W2 pre-swizzle.
//      Hblk layout [B1][NBIN4]; hist reads ei via int4 (4 edges/load).
//      N_EDGES%4==0 and base%2048==0 -> each int4 fully in or out. ----
__global__ __launch_bounds__(256) void k_prep_hist(
    const float* __restrict__ W1, ushort_t* __restrict__ W1p,
    const float* __restrict__ W2, ushort_t* __restrict__ W2p,
    const int* __restrict__ ei, int* __restrict__ Hblk)
{
    int b = blockIdx.x;
    if (b < B1) {
        __shared__ int h[NBIN4];
        for (int i = threadIdx.x; i < NBIN4; i += 256) h[i] = 0;
        __syncthreads();
        int base = b * EB;
        #pragma unroll
        for (int c = 0; c < EB / 1024; ++c) {      // 2 iters of int4
            int idx = base + (c * 256 + threadIdx.x) * 4;
            if (idx < N_EDGES) {
                int4 d4 = *(const int4*)&ei[N_EDGES + idx];
                atomicAdd(&h[((uint_t)d4.x) >> 7], 1);
                atomicAdd(&h[((uint_t)d4.y) >> 7], 1);
                atomicAdd(&h[((uint_t)d4.z) >> 7], 1);
                atomicAdd(&h[((uint_t)d4.w) >> 7], 1);
            }
        }
        __syncthreads();
        for (int i = threadIdx.x; i < NBIN4; i += 256)
            Hblk[b * NBIN4 + i] = h[i];                // coalesced
        return;
    }
    int i = (b - B1) * 256 + threadIdx.x;
    if (i < 8192) {
        int j = i & 7, lane = (i >> 3) & 63, nt = (i >> 9) & 3, s = i >> 11;
        int k = s * 32 + (lane >> 4) * 8 + j;
        int n = nt * 16 + (lane & 15);
        W1p[i] = f2bf(W1[k * C1 + n]);
    } else {
        int i2 = i - 8192;
        if (i2 < 3072) {
            int j = i2 & 7, lane = (i2 >> 3) & 63, khalf = (i2 >> 9) & 1, nt = i2 >> 10;
            int n = nt * 16 + (lane & 15);
            int k = khalf * 32 + (lane >> 4) * 8 + j;
            float v = (n < C2) ? W2[k * C2 + n] : 0.f;
            W2p[i2] = f2bf(v);
        }
    }
}

// ---- colscan: 4 bins per block via int4 componentwise scan ----
__global__ __launch_bounds__(512) void k_colscan(
    int* __restrict__ Hblk, int* __restrict__ totB)
{
    __shared__ i32x4 s[512];
    int g = blockIdx.x * 4;            // bin group base
    int t = threadIdx.x;
    i32x4 run = {0, 0, 0, 0};
    for (int c = 0; c < 2; ++c) {
        int i = c * 512 + t;
        i32x4 v = {0, 0, 0, 0};
        if (i < B1) v = *(const i32x4*)&Hblk[i * NBIN4 + g];
        s[t] = v;
        __syncthreads();
        for (int off = 1; off < 512; off <<= 1) {
            i32x4 u = {0, 0, 0, 0};
            if (t >= off) u = s[t - off];
            __syncthreads();
            s[t] += u;
            __syncthreads();
        }
        if (i < B1) *(i32x4*)&Hblk[i * NBIN4 + g] = s[t] - v + run;
        i32x4 tot = s[511];
        __syncthreads();
        run += tot;
    }
    if (t == 0) *(i32x4*)&totB[g] = run;
}

// ---- basescan: exclusive scan of 782 bin totals ----
__global__ __launch_bounds__(512) void k_basescan(
    const int* __restrict__ totB, int* __restrict__ baseB,
    int* __restrict__ rowptr)
{
    __shared__ int s[512];
    int t = threadIdx.x;
    int run = 0;
    for (int c = 0; c < 2; ++c) {
        int i = c * 512 + t;
        int v = (i < NBIN) ? totB[i] : 0;
        s[t] = v;
        __syncthreads();
        for (int off = 1; off < 512; off <<= 1) {
            int u = (t >= off) ? s[t - off] : 0;
            __syncthreads();
            s[t] += u;
            __syncthreads();
        }
        if (i < NBIN) baseB[i] = s[t] - v + run;
        int tot = s[511];
        __syncthreads();
        run += tot;
    }
    if (t == 0) { baseB[NBIN] = run; rowptr[N_NODES] = run; }
}

// ---- merged: scatter1 (block-local counting sort, int4 loads) || GEMM1 ----
__global__ __launch_bounds__(256) void k_gemm1_sc1(
    const float* __restrict__ x, const ushort_t* __restrict__ W1p,
    const float* __restrict__ as1, const float* __restrict__ ad1,
    ushort_t* __restrict__ H1, float* __restrict__ s1, float* __restrict__ d1,
    const int* __restrict__ ei, const float* __restrict__ ea,
    const int* __restrict__ Hblk, const int* __restrict__ baseB,
    int2* __restrict__ coarse)
{
    int b = blockIdx.x;
    int t = threadIdx.x;
    if (b < B1) {
        __shared__ int    cnt[NBIN];     // hist, then cursor
        __shared__ int    loff[NBIN];    // local exclusive offsets
        __shared__ int    gof[NBIN];     // global base - loff
        __shared__ int    ssc[256];
        __shared__ int2   sbuf[EB];      // 16 KB bin-sorted edges
        __shared__ ushort_t sbin[EB];    // 4 KB bin ids
        int base = b * EB;
        int nE = min(EB, N_EDGES - base);
        for (int i = t; i < NBIN; i += 256) cnt[i] = 0;
        __syncthreads();
        int myd[8];                      // full dst per edge (int4 groups)
        #pragma unroll
        for (int c = 0; c < 2; ++c) {
            int idx = base + (c * 256 + t) * 4;
            if (idx < N_EDGES) {
                int4 d4 = *(const int4*)&ei[N_EDGES + idx];
                myd[c * 4 + 0] = d4.x;
                myd[c * 4 + 1] = d4.y;
                myd[c * 4 + 2] = d4.z;
                myd[c * 4 + 3] = d4.w;
                atomicAdd(&cnt[((uint_t)d4.x) >> 7], 1);
                atomicAdd(&cnt[((uint_t)d4.y) >> 7], 1);
                atomicAdd(&cnt[((uint_t)d4.z) >> 7], 1);
                atomicAdd(&cnt[((uint_t)d4.w) >> 7], 1);
            }
        }
        __syncthreads();
        {
            int b4 = t * 4;
            int a0 = (b4 + 0 < NBIN) ? cnt[b4 + 0] : 0;
            int a1 = (b4 + 1 < NBIN) ? cnt[b4 + 1] : 0;
            int a2 = (b4 + 2 < NBIN) ? cnt[b4 + 2] : 0;
            int a3 = (b4 + 3 < NBIN) ? cnt[b4 + 3] : 0;
            int tsum = a0 + a1 + a2 + a3;
            ssc[t] = tsum;
            __syncthreads();
            for (int off = 1; off < 256; off <<= 1) {
                int u = (t >= off) ? ssc[t - off] : 0;
                __syncthreads();
                ssc[t] += u;
                __syncthreads();
            }
            int exc = ssc[t] - tsum;
            if (b4 + 0 < NBIN) loff[b4 + 0] = exc;
            if (b4 + 1 < NBIN) loff[b4 + 1] = exc + a0;
            if (b4 + 2 < NBIN) loff[b4 + 2] = exc + a0 + a1;
            if (b4 + 3 < NBIN) loff[b4 + 3] = exc + a0 + a1 + a2;
        }
        __syncthreads();
        for (int i = t; i < NBIN; i += 256) {
            gof[i] = baseB[i] + Hblk[b * NBIN4 + i] - loff[i];
            cnt[i] = loff[i];
        }
        __syncthreads();
        #pragma unroll
        for (int c = 0; c < 2; ++c) {
            int idx = base + (c * 256 + t) * 4;
            if (idx < N_EDGES) {
                int4  s4 = *(const int4*)&ei[idx];
                float4 e4 = *(const float4*)&ea[idx];
                int ss[4] = {s4.x, s4.y, s4.z, s4.w};
                float ee[4] = {e4.x, e4.y, e4.z, e4.w};
                #pragma unroll
                for (int k = 0; k < 4; ++k) {
                    int d = myd[c * 4 + k];
                    int bn = ((uint_t)d) >> 7;
                    int p = atomicAdd(&cnt[bn], 1);
                    sbuf[p] = make_int2(ss[k] | ((d & (NPB - 1)) << 24),
                                        __float_as_int(ee[k]));
                    sbin[p] = (ushort_t)bn;
                }
            }
        }
        __syncthreads();
        for (int j = t; j < nE; j += 256) {
            int bn = sbin[j];
            coarse[gof[bn] + j] = sbuf[j];
        }
        return;
    }
    // GEMM1 half: fragments from x (fp32) with in-register bf16 convert
    int tile = ((b - B1) * 256 + t) >> 6;
    int lane = t & 63;
    if (tile >= N_NODES / 16) return;
    int quad = lane >> 4, lo = lane & 15;
    const float* arow = x + ((size_t)tile * 16 + lo) * IN_F + quad * 8;
    short8 a0 = ld8f2bf(arow);                   // k = 0*32 + quad*8+j
    short8 a1 = ld8f2bf(arow + 32);
    short8 a2 = ld8f2bf(arow + 64);
    short8 a3 = ld8f2bf(arow + 96);
    f32x4 acc[4] = {{0,0,0,0},{0,0,0,0},{0,0,0,0},{0,0,0,0}};
    #pragma unroll
    for (int nt = 0; nt < 4; ++nt) {
        short8 b0 = *(const short8*)&W1p[((0 * 4 + nt) * 64 + lane) * 8];
        short8 b1 = *(const short8*)&W1p[((1 * 4 + nt) * 64 + lane) * 8];
        short8 b2 = *(const short8*)&W1p[((2 * 4 + nt) * 64 + lane) * 8];
        short8 b3 = *(const short8*)&W1p[((3 * 4 + nt) * 64 + lane) * 8];
        acc[nt] = __builtin_amdgcn_mfma_f32_16x16x32_bf16(a0, b0, acc[nt], 0, 0, 0);
        acc[nt] = __builtin_amdgcn_mfma_f32_16x16x32_bf16(a1, b1, acc[nt], 0, 0, 0);
        acc[nt] = __builtin_amdgcn_mfma_f32_16x16x32_bf16(a2, b2, acc[nt], 0, 0, 0);
        acc[nt] = __builtin_amdgcn_mfma_f32_16x16x32_bf16(a3, b3, acc[nt], 0, 0, 0);
    }
    int nb = tile * 16 + quad * 4;               // C/D: col=lo, row=quad*4+reg
    float ps[4][4], pd[4][4];
    #pragma unroll
    for (int nt = 0; nt < 4; ++nt) {
        int cb = nt * 16 + lo;
        float av = as1[cb], dv = ad1[cb];
        #pragma unroll
        for (int r = 0; r < 4; ++r) {
            H1[(size_t)(nb + r) * C1 + cb] = f2bf(acc[nt][r]);
            ps[nt][r] = acc[nt][r] * av;
            pd[nt][r] = acc[nt][r] * dv;
        }
    }
    #pragma unroll
    for (int nt = 0; nt < 4; ++nt)
        #pragma unroll
        for (int r = 0; r < 4; ++r)
            #pragma unroll
            for (int off = 1; off < 8; off <<= 1) {
                ps[nt][r] += __shfl_xor(ps[nt][r], off);
                pd[nt][r] += __shfl_xor(pd[nt][r], off);
            }
    if ((lo & 7) == 0) {
        int hh = lo >> 3;
        #pragma unroll
        for (int nt = 0; nt < 4; ++nt) {
            int h = nt * 2 + hh;
            #pragma unroll
            for (int r = 0; r < 4; ++r) {
                s1[(nb + r) * NH1 + h] = ps[nt][r];
                d1[(nb + r) * NH1 + h] = pd[nt][r];
            }
        }
    }
}

// ---- scatter2: one block per 128-node bucket (782 blocks) ----
__global__ __launch_bounds__(256) void k_scatter2(
    const int2* __restrict__ coarse, const int* __restrict__ baseB,
    int2* __restrict__ edges, int* __restrict__ rowptr)
{
    __shared__ int2 buf[S2CAP];          // 20 KB
    __shared__ int h[NPB];
    __shared__ int ssc[256];
    int bin = blockIdx.x, t = threadIdx.x;
    int s0 = baseB[bin], s1b = baseB[bin + 1];
    int n = s1b - s0;
    if (t < NPB) h[t] = 0;
    __syncthreads();
    for (int j = t; j < n; j += 256)
        atomicAdd(&h[(uint_t)coarse[s0 + j].x >> 24], 1);
    __syncthreads();
    int v = (t < NPB) ? h[t] : 0;
    ssc[t] = v;
    __syncthreads();
    for (int off = 1; off < 256; off <<= 1) {
        int u = (t >= off) ? ssc[t - off] : 0;
        __syncthreads();
        ssc[t] += u;
        __syncthreads();
    }
    int exc = ssc[t] - v;
    if (t < NPB) {
        int node = bin * NPB + t;
        if (node < N_NODES) rowptr[node] = s0 + exc;
        h[t] = exc;                      // h becomes cursor
    }
    __syncthreads();
    for (int j = t; j < n; j += 256) {
        int2 c = coarse[s0 + j];         // L2-hot second read
        int ln = (uint_t)c.x >> 24;
        int p = atomicAdd(&h[ln], 1);
        int2 ov = make_int2(c.x & 0x00FFFFFF, c.y);
        if (p < S2CAP) buf[p] = ov;
        else           edges[s0 + p] = ov;   // overflow fallback (~never)
    }
    __syncthreads();
    int nl = n < S2CAP ? n : S2CAP;
    for (int j = t; j < nl; j += 256)
        edges[s0 + j] = buf[j];              // coalesced write-out
}

// ============ attention / aggregation ============

// ---- K_node1 PAIRED (fused logit1), 8-deep gather unroll (validated
//      optimum: 16-deep cost occupancy, null gain). ----
__global__ __launch_bounds__(256) void k_node1(
    const int* __restrict__ rowptr, const int2* __restrict__ edges,
    const float* __restrict__ s1, const float* __restrict__ d1,
    const float* __restrict__ ae1,
    const ushort_t* __restrict__ H1, ushort_t* __restrict__ out1r)
{
    __shared__ uint_t sm_s[4][2][33];     // +1 pad: halves hit distinct banks
    __shared__ float  sm_pf[4][2][8][33]; // [half][head][edge], +1 pad
    int w2 = (blockIdx.x * blockDim.x + threadIdx.x) >> 6;   // pair id
    int lane = threadIdx.x & 63;
    int wv = (threadIdx.x >> 6) & 3;
    if (w2 >= NPAIR) return;
    int half = lane >> 5, lo32 = lane & 31;
    int node = 2 * w2 + half;
    int h = lo32 >> 2;                     // head of features 2*lo32, 2*lo32+1
    uint_t fb = (uint_t)lo32 << 2;         // byte offset of this lane's dword
    int jb = rowptr[node], je = rowptr[node + 1];
    int cnt = je - jb;
    int maxc = max(cnt, __shfl_xor(cnt, 32));   // uniform loop bound
    float4 d1a = *(const float4*)(d1 + node * NH1);
    float4 d1b = *(const float4*)(d1 + node * NH1 + 4);
    float4 aea = *(const float4*)(ae1);
    float4 aeb = *(const float4*)(ae1 + 4);
    float den = 0.f, acc0 = 0.f, acc1 = 0.f;
    const float* pfh = &sm_pf[wv][half][h][0];
    const uint_t* sms = &sm_s[wv][half][0];
    for (int base = 0; base < maxc; base += 32) {
        int loc = base + lo32;
        uint_t soff = 0;
        float pf[8] = {0.f, 0.f, 0.f, 0.f, 0.f, 0.f, 0.f, 0.f};
        if (loc < cnt) {
            int2 ed = edges[jb + loc];
            soff = (uint_t)ed.x << 7;
            float ea = __int_as_float(ed.y);
            const float* s1r = s1 + (size_t)ed.x * NH1;
            float4 sa = *(const float4*)s1r;
            float4 sb = *(const float4*)(s1r + 4);
            pf[0] = __expf(lrelu(fmaf(ea, aea.x, sa.x + d1a.x)));
            pf[1] = __expf(lrelu(fmaf(ea, aea.y, sa.y + d1a.y)));
            pf[2] = __expf(lrelu(fmaf(ea, aea.z, sa.z + d1a.z)));
            pf[3] = __expf(lrelu(fmaf(ea, aea.w, sa.w + d1a.w)));
            pf[4] = __expf(lrelu(fmaf(ea, aeb.x, sb.x + d1b.x)));
            pf[5] = __expf(lrelu(fmaf(ea, aeb.y, sb.y + d1b.y)));
            pf[6] = __expf(lrelu(fmaf(ea, aeb.z, sb.z + d1b.z)));
            pf[7] = __expf(lrelu(fmaf(ea, aeb.w, sb.w + d1b.w)));
        }
        sm_s[wv][half][lo32] = soff;
        #pragma unroll
        for (int k = 0; k < 8; ++k) sm_pf[wv][half][k][lo32] = pf[k];
        __builtin_amdgcn_wave_barrier();
        int steps = (min(32, maxc - base) + 7) & ~7;   // pad slots have p=0
        for (int e = 0; e < steps; e += 8) {
            uint_t so[8];
            float  p[8];
            uint_t u[8];
            #pragma unroll
            for (int k = 0; k < 8; ++k) {
                so[k] = sms[e + k];
                p[k]  = pfh[e + k];
            }
            #pragma unroll
            for (int k = 0; k < 8; ++k)
                u[k] = *(const uint_t*)((const char*)H1 + (so[k] + fb));
            #pragma unroll
            for (int k = 0; k < 8; ++k) {
                den += p[k];
                acc0 = fmaf(p[k], __uint_as_float(u[k] << 16), acc0);
                acc1 = fmaf(p[k], __uint_as_float(u[k] & 0xffff0000u), acc1);
            }
        }
        __builtin_amdgcn_wave_barrier();
    }
    float inv = 1.f / (den + 1e-16f);
    float o0 = acc0 * inv, o1 = acc1 * inv;
    float r0 = o0 > 0.f ? o0 : __expf(o0) - 1.f;   // elu
    float r1 = o1 > 0.f ? o1 : __expf(o1) - 1.f;
    uint_t pk = (uint_t)f2bf(r0) | ((uint_t)f2bf(r1) << 16);
    *(uint_t*)((char*)out1r + (size_t)node * 128 + fb) = pk;   // all 64 lanes
}

// ---- K_gemm2 (MFMA): H2 stride-64 (128-B-aligned rows: 1 line/edge
//      for node2's gathers — packing to 80-B rows straddles lines, R12) ----
__global__ __launch_bounds__(256) void k_gemm2(
    const ushort_t* __restrict__ out1r, const ushort_t* __restrict__ W2p,
    const float* __restrict__ as2, const float* __restrict__ ad2,
    ushort_t* __restrict__ H2, float* __restrict__ s2, float* __restrict__ d2)
{
    int tile = (blockIdx.x * blockDim.x + threadIdx.x) >> 6;
    int lane = threadIdx.x & 63;
    if (tile >= N_NODES / 16) return;
    int quad = lane >> 4, lo = lane & 15;
    const ushort_t* arow = out1r + ((size_t)tile * 16 + lo) * C1 + quad * 8;
    short8 a0 = *(const short8*)arow;
    short8 a1 = *(const short8*)(arow + 32);
    f32x4 acc[3] = {{0,0,0,0},{0,0,0,0},{0,0,0,0}};
    #pragma unroll
    for (int nt = 0; nt < 3; ++nt) {
        short8 b0 = *(const short8*)&W2p[((nt * 2 + 0) * 64 + lane) * 8];
        short8 b1 = *(const short8*)&W2p[((nt * 2 + 1) * 64 + lane) * 8];
        acc[nt] = __builtin_amdgcn_mfma_f32_16x16x32_bf16(a0, b0, acc[nt], 0, 0, 0);
        acc[nt] = __builtin_amdgcn_mfma_f32_16x16x32_bf16(a1, b1, acc[nt], 0, 0, 0);
    }
    float ps0 = 0.f, ps1 = 0.f, ps2 = 0.f, ps3 = 0.f;
    float pd0 = 0.f, pd1 = 0.f, pd2 = 0.f, pd3 = 0.f;
    #pragma unroll
    for (int nt = 0; nt < 3; ++nt) {
        int cb = nt * 16 + lo;
        float a2 = cb < C2 ? as2[cb] : 0.f;
        float b2 = cb < C2 ? ad2[cb] : 0.f;
        float v0 = acc[nt][0], v1 = acc[nt][1], v2 = acc[nt][2], v3 = acc[nt][3];
        int nb = tile * 16 + quad * 4;
        H2[(size_t)(nb + 0) * C1 + cb] = f2bf(v0);
        H2[(size_t)(nb + 1) * C1 + cb] = f2bf(v1);
        H2[(size_t)(nb + 2) * C1 + cb] = f2bf(v2);
        H2[(size_t)(nb + 3) * C1 + cb] = f2bf(v3);
        ps0 = fmaf(v0, a2, ps0); ps1 = fmaf(v1, a2, ps1);
        ps2 = fmaf(v2, a2, ps2); ps3 = fmaf(v3, a2, ps3);
        pd0 = fmaf(v0, b2, pd0); pd1 = fmaf(v1, b2, pd1);
        pd2 = fmaf(v2, b2, pd2); pd3 = fmaf(v3, b2, pd3);
    }
    #pragma unroll
    for (int off = 1; off < 16; off <<= 1) {
        ps0 += __shfl_xor(ps0, off); ps1 += __shfl_xor(ps1, off);
        ps2 += __shfl_xor(ps2, off); ps3 += __shfl_xor(ps3, off);
        pd0 += __shfl_xor(pd0, off); pd1 += __shfl_xor(pd1, off);
        pd2 += __shfl_xor(pd2, off); pd3 += __shfl_xor(pd3, off);
    }
    if (lo == 0) {
        int nb = tile * 16 + quad * 4;
        s2[nb + 0] = ps0; s2[nb + 1] = ps1; s2[nb + 2] = ps2; s2[nb + 3] = ps3;
        d2[nb + 0] = pd0; d2[nb + 1] = pd1; d2[nb + 2] = pd2; d2[nb + 3] = pd3;
    }
}

// ---- K_node2 PAIRED (fused logit2 + log_softmax), 8-deep gather unroll ----
__global__ __launch_bounds__(256) void k_node2(
    const int* __restrict__ rowptr, const int2* __restrict__ edges,
    const float* __restrict__ s2, const float* __restrict__ d2,
    const float* __restrict__ ae2,
    const ushort_t* __restrict__ H2, float* __restrict__ out)
{
    __shared__ int2 sp[4][2][33];          // (src<<7, p_float_bits), +1 pad
    int w2 = (blockIdx.x * blockDim.x + threadIdx.x) >> 6;
    int lane = threadIdx.x & 63;
    int wv = (threadIdx.x >> 6) & 3;
    if (w2 >= NPAIR) return;
    int half = lane >> 5, lo32 = lane & 31;
    int node = 2 * w2 + half;
    int fi = lo32 < 20 ? lo32 : 19;
    uint_t fb = (uint_t)fi << 2;
    int jb = rowptr[node], je = rowptr[node + 1];
    int cnt = je - jb;
    int maxc = max(cnt, __shfl_xor(cnt, 32));
    float d2v = d2[node];
    float aev = ae2[0];
    float den = 0.f, acc0 = 0.f, acc1 = 0.f;
    const int2* spp = &sp[wv][half][0];
    for (int base = 0; base < maxc; base += 32) {
        int loc = base + lo32;
        int soff = 0; float p = 0.f;
        if (loc < cnt) {
            int2 ed = edges[jb + loc];
            soff = ed.x << 7;
            p = __expf(lrelu(s2[ed.x] + d2v + __int_as_float(ed.y) * aev));
        }
        sp[wv][half][lo32] = make_int2(soff, __float_as_int(p));
        __builtin_amdgcn_wave_barrier();
        int steps = (min(32, maxc - base) + 7) & ~7;   // pad slots have p=0
        for (int e = 0; e < steps; e += 8) {
            int2 ed[8];
            uint_t u[8];
            #pragma unroll
            for (int k = 0; k < 8; ++k) ed[k] = spp[e + k];
            #pragma unroll
            for (int k = 0; k < 8; ++k)
                u[k] = *(const uint_t*)((const char*)H2 + ((uint_t)ed[k].x + fb));
            #pragma unroll
            for (int k = 0; k < 8; ++k) {
                float pk = __int_as_float(ed[k].y);
                den += pk;
                acc0 = fmaf(pk, __uint_as_float(u[k] << 16), acc0);
                acc1 = fmaf(pk, __uint_as_float(u[k] & 0xffff0000u), acc1);
            }
        }
        __builtin_amdgcn_wave_barrier();
    }
    float inv = 1.f / (den + 1e-16f);
    float o0 = acc0 * inv, o1 = acc1 * inv;
    float v0 = lo32 < 20 ? o0 : -INFINITY;
    float v1 = lo32 < 20 ? o1 : -INFINITY;
    float m = fmaxf(v0, v1);
    #pragma unroll
    for (int off = 16; off; off >>= 1) m = fmaxf(m, __shfl_xor(m, off));
    float pp = lo32 < 20 ? __expf(v0 - m) + __expf(v1 - m) : 0.f;
    #pragma unroll
    for (int off = 16; off; off >>= 1) pp += __shfl_xor(pp, off);
    float ls = __logf(pp);
    if (lo32 < 20) {
        float2 st = make_float2(v0 - m - ls, v1 - m - ls);
        *(float2*)(out + (size_t)node * C2 + 2 * fi) = st;
    }
}

extern "C" void kernel_launch(void* const* d_in, const int* in_sizes, int n_in,
                              void* d_out, int out_size, void* d_ws, size_t ws_size,
                              hipStream_t stream)
{
    const float* x   = (const float*)d_in[0];
    const int*   ei  = (const int*)  d_in[1];
    const float* ea  = (const float*)d_in[2];
    const float* W1  = (const float*)d_in[3];
    const float* as1 = (const float*)d_in[4];
    const float* ad1 = (const float*)d_in[5];
    const float* ae1 = (const float*)d_in[6];
    const float* W2  = (const float*)d_in[7];
    const float* as2 = (const float*)d_in[8];
    const float* ad2 = (const float*)d_in[9];
    const float* ae2 = (const float*)d_in[10];
    float* out = (float*)d_out;

    // workspace layout (4-byte units):
    //   H1 [0,3.2M) -> reused as H2 (stride-64); out1r region [3.2M,6.4M)
    //     first holds CSR temps (Hblk 782*784 ints, totB, baseB), then
    //     out1r (k_node1 writes)
    //   coarse [6.4M,9.6M); edges [9.6M,12.8M)
    float*    ws     = (float*)d_ws;
    ushort_t* H1     = (ushort_t*)ws;                 // [0, 3.2M)  bf16
    ushort_t* H2     = (ushort_t*)ws;                 //   alias (after node1)
    ushort_t* out1r  = (ushort_t*)(ws + 3200000);     // [3.2M, 6.4M)
    int*      Hblk   = (int*)(ws + 3200000);          //   alias: 782*784 ints
    int*      totB   = (int*)(ws + 3820000);          //   alias: 784 ints
    int*      baseB  = (int*)(ws + 3821000);          //   alias: 783 ints
    int2*     coarse = (int2*)(ws + 6400000);         // [6.4M, 9.6M) packed
    int2*     edges  = (int2*)(ws + 9600000);         // [9.6M, 12.8M)
    float*    s1     = ws + 16000000;                 // [16.0M, 16.8M)
    float*    d1     = ws + 16800000;                 // [16.8M, 17.6M)
    int*      rowptr = (int*)(ws + 17600000);         // 100,001 ints
    float*    s2     = ws + 17700008;                 // 100,000
    float*    d2     = ws + 17800008;                 // 100,000
    ushort_t* W2p    = (ushort_t*)(ws + 17900008);    // 3072 bf16 (1536 w)
    ushort_t* W1p    = (ushort_t*)(ws + 17901544);    // 8192 bf16 (4096 w)

    k_prep_hist <<<B1 + WPREP_BLKS, 256, 0, stream>>>(
        W1, W1p, W2, W2p, ei, Hblk);
    k_colscan   <<<NBIN4 / 4, 512, 0, stream>>>(Hblk, totB);
    k_basescan  <<<1, 512, 0, stream>>>(totB, baseB, rowptr);
    k_gemm1_sc1 <<<B1 + GEMM1_BLKS, 256, 0, stream>>>(
        x, W1p, as1, ad1, H1, s1, d1, ei, ea, Hblk, baseB, coarse);
    k_scatter2  <<<NBIN, 256, 0, stream>>>(coarse, baseB, edges, rowptr);
    k_node1     <<<(NPAIR + 3) / 4, 256, 0, stream>>>(rowptr, edges, s1, d1, ae1,
                                                      H1, out1r);
    k_gemm2     <<<(N_NODES / 16 + 3) / 4, 256, 0, stream>>>(out1r, W2p, as2, ad2,
                                                             H2, s2, d2);
    k_node2     <<<(NPAIR + 3) / 4, 256, 0, stream>>>(rowptr, edges, s2, d2, ae2,
                                                      H2, out);
}